// Round 10
// baseline (307.324 us; speedup 1.0000x reference)
//
#include <hip/hip_runtime.h>

// Problem shapes (fixed by reference setup_inputs)
#define B_DIM 1024
#define C_DIM 128
#define K_DIM 1024
#define E_DIM 4
#define EMBED_ELEMS (B_DIM * C_DIM * E_DIM)
#define OH_ELEMS ((size_t)B_DIM * C_DIM * K_DIM)   // 134,217,728 dwords

// ---------------------------------------------------------------------------
// K1: argmin + embed (unchanged, proven exact). One block = 4 waves, same c;
// each wave owns 8 b-rows. Grid = 4096 blocks. Writes idx (B,C) i32 + embed.
// ---------------------------------------------------------------------------
__global__ __launch_bounds__(256) void vq_argmin_kernel(
    const float* __restrict__ cw_q,      // (B, C*E) f32
    const float* __restrict__ codebook,  // (C, K, E) f32
    float* __restrict__ out,             // embed at offset 0
    int* __restrict__ idx_out)           // (B, C) int32 in d_ws
{
    __shared__ float4 lds_cb[K_DIM];     // 16 KB: codebook[c]

    const int lane = threadIdx.x & 63;
    const int wave = threadIdx.x >> 6;
    const int bid  = blockIdx.x;
    const int c      = bid >> 5;         // 32 blocks per c
    const int btile  = bid & 31;
    const int b_base = btile * 32 + wave * 8;

    const float4* cb4 = (const float4*)codebook + (size_t)c * K_DIM;
    const float4* x4  = (const float4*)cw_q;    // (B, C) float4
    float4* emb4 = (float4*)out;                // (B, C) float4

    for (int t = threadIdx.x; t < K_DIM; t += 256)
        lds_cb[t] = cb4[t];
    __syncthreads();

    // ||b_k||^2 in f64 (exact from f32 inputs -> true ordering, proven R3/R4).
    double bsq[16];
#pragma unroll
    for (int j = 0; j < 16; ++j) {
        const float4 cb = lds_cb[j * 64 + lane];
        const double bx = (double)cb.x, by = (double)cb.y,
                     bz = (double)cb.z, bw = (double)cb.w;
        bsq[j] = bx * bx + by * by + bz * bz + bw * bw;
    }

    for (int g = 0; g < 2; ++g) {
        double x2[4][4];
#pragma unroll
        for (int ii = 0; ii < 4; ++ii) {
            const int b = b_base + g * 4 + ii;
            const float4 x = x4[(size_t)b * C_DIM + c];
            x2[ii][0] = -2.0 * (double)x.x;
            x2[ii][1] = -2.0 * (double)x.y;
            x2[ii][2] = -2.0 * (double)x.z;
            x2[ii][3] = -2.0 * (double)x.w;
        }

        double bestd[4];
        int    bestk[4];
#pragma unroll
        for (int ii = 0; ii < 4; ++ii) { bestd[ii] = INFINITY; bestk[ii] = 0x7fffffff; }

        for (int j = 0; j < 16; ++j) {
            const float4 cb = lds_cb[j * 64 + lane];
            const double bx = (double)cb.x, by = (double)cb.y,
                         bz = (double)cb.z, bw = (double)cb.w;
            const int k = j * 64 + lane;
#pragma unroll
            for (int ii = 0; ii < 4; ++ii) {
                // d' = bsq - 2*dot  (x_sq constant over k: argmin-invariant)
                const double d = fma(bw, x2[ii][3],
                                 fma(bz, x2[ii][2],
                                 fma(by, x2[ii][1],
                                 fma(bx, x2[ii][0], bsq[j]))));
                if (d < bestd[ii]) { bestd[ii] = d; bestk[ii] = k; }
            }
        }

        // Wave argmin, lexicographic (d, k), 4 rows interleaved.
#pragma unroll
        for (int off = 32; off >= 1; off >>= 1) {
#pragma unroll
            for (int ii = 0; ii < 4; ++ii) {
                const double od = __shfl_xor(bestd[ii], off);
                const int    oi = __shfl_xor(bestk[ii], off);
                if (od < bestd[ii] || (od == bestd[ii] && oi < bestk[ii])) {
                    bestd[ii] = od; bestk[ii] = oi;
                }
            }
        }

#pragma unroll
        for (int ii = 0; ii < 4; ++ii) {
            const int b  = b_base + g * 4 + ii;
            const int bi = bestk[ii];
            if (lane == 0) {
                emb4[(size_t)b * C_DIM + c] = lds_cb[bi];
                idx_out[b * C_DIM + c]      = bi;   // cached store: K2 reads it
            }
        }
    }
}

// ---------------------------------------------------------------------------
// K2: fill-mimic one-hot (unchanged from R9). Flat grid-stride, plain dword
// stores, trivial body. Idempotent: rewrites identical bytes each launch.
// ---------------------------------------------------------------------------
__global__ __launch_bounds__(256) void vq_onehot_fill(
    const int* __restrict__ idx_in,      // (B, C) flat, 512 KB (L2-resident)
    float* __restrict__ out)             // one_hot at EMBED_ELEMS
{
    float* oh = out + EMBED_ELEMS;
    const size_t T = (size_t)gridDim.x * 256;
    size_t e = (size_t)blockIdx.x * 256 + threadIdx.x;
#pragma unroll 4
    for (; e < OH_ELEMS; e += T) {
        const int row = (int)(e >> 10);          // flat (b*C+c) row
        const int k   = (int)(e & (K_DIM - 1));  // k within row
        oh[e] = (k == idx_in[row]) ? 1.0f : 0.0f;
    }
}

extern "C" void kernel_launch(void* const* d_in, const int* in_sizes, int n_in,
                              void* d_out, int out_size, void* d_ws, size_t ws_size,
                              hipStream_t stream) {
    const float* cw_q     = (const float*)d_in[0];
    const float* codebook = (const float*)d_in[1];
    float* out = (float*)d_out;
    int*   idx = (int*)d_ws;   // 512 KB scratch

    vq_argmin_kernel<<<C_DIM * (B_DIM / 32), 256, 0, stream>>>(cw_q, codebook, out, idx);
    // PROBE (this round only): K2 launched twice. K2 is idempotent, so output
    // is unchanged; T10 - T9 isolates K2's duration, T9 - K2 gives K1's.
    vq_onehot_fill<<<8192, 256, 0, stream>>>(idx, out);
    vq_onehot_fill<<<8192, 256, 0, stream>>>(idx, out);
}

// Round 11
// 175.322 us; speedup vs baseline: 1.7529x; 1.7529x over previous
//
#include <hip/hip_runtime.h>

// Problem shapes (fixed by reference setup_inputs)
#define B_DIM 1024
#define C_DIM 128
#define K_DIM 1024
#define E_DIM 4
#define EMBED_ELEMS (B_DIM * C_DIM * E_DIM)
#define OH_ELEMS ((size_t)B_DIM * C_DIM * K_DIM)   // 134,217,728 dwords

typedef float f32x4 __attribute__((ext_vector_type(4)));

// ---------------------------------------------------------------------------
// K_fused: argmin + embed (proven-exact f64 path, unchanged) PLUS a 128 KB
// contiguous zero-fill slab of the one-hot output per block. The zero stores
// are issued before the f64 scan and drain while it runs (separate pipes).
// Grid = 4096 blocks: covers all (b,c) rows AND all 512 MB of zeros.
// ---------------------------------------------------------------------------
__global__ __launch_bounds__(256) void vq_fused_kernel(
    const float* __restrict__ cw_q,      // (B, C*E) f32
    const float* __restrict__ codebook,  // (C, K, E) f32
    float* __restrict__ out,             // [embed | one_hot]
    int* __restrict__ idx_out)           // (B, C) int32 in d_ws
{
    __shared__ float4 lds_cb[K_DIM];     // 16 KB: codebook[c]

    const int lane = threadIdx.x & 63;
    const int wave = threadIdx.x >> 6;
    const int bid  = blockIdx.x;
    const int c      = bid >> 5;         // 32 blocks per c
    const int btile  = bid & 31;
    const int b_base = btile * 32 + wave * 8;

    const float4* cb4 = (const float4*)codebook + (size_t)c * K_DIM;
    const float4* x4  = (const float4*)cw_q;    // (B, C) float4
    float4* emb4 = (float4*)out;                // (B, C) float4

    // 1) Stage codebook into LDS.
    for (int t = threadIdx.x; t < K_DIM; t += 256)
        lds_cb[t] = cb4[t];

    // 2) Load this wave's 8 x-rows BEFORE the store burst (so the compiler's
    //    wait for them is vmcnt(32), not a full drain).
    float4 xr[8];
#pragma unroll
    for (int i = 0; i < 8; ++i)
        xr[i] = x4[(size_t)(b_base + i) * C_DIM + c];

    __syncthreads();

    // 3) Zero-fill burst: 128 KB contiguous per block, fire-and-forget.
    //    Drains during the f64 compute below.
    {
        f32x4* dst = (f32x4*)(out + EMBED_ELEMS) + (size_t)bid * 8192
                   + threadIdx.x;
        const f32x4 z = {0.f, 0.f, 0.f, 0.f};
#pragma unroll
        for (int i = 0; i < 32; ++i)
            dst[i * 256] = z;
    }

    // 4) ||b_k||^2 in f64 (exact from f32 inputs -> true ordering, R3-proven).
    double bsq[16];
#pragma unroll
    for (int j = 0; j < 16; ++j) {
        const float4 cb = lds_cb[j * 64 + lane];
        const double bx = (double)cb.x, by = (double)cb.y,
                     bz = (double)cb.z, bw = (double)cb.w;
        bsq[j] = bx * bx + by * by + bz * bz + bw * bw;
    }

    // 5) Argmin scan, 2 groups of 4 rows.
    for (int g = 0; g < 2; ++g) {
        double x2[4][4];
#pragma unroll
        for (int ii = 0; ii < 4; ++ii) {
            const float4 x = xr[g * 4 + ii];
            x2[ii][0] = -2.0 * (double)x.x;
            x2[ii][1] = -2.0 * (double)x.y;
            x2[ii][2] = -2.0 * (double)x.z;
            x2[ii][3] = -2.0 * (double)x.w;
        }

        double bestd[4];
        int    bestk[4];
#pragma unroll
        for (int ii = 0; ii < 4; ++ii) { bestd[ii] = INFINITY; bestk[ii] = 0x7fffffff; }

        for (int j = 0; j < 16; ++j) {
            const float4 cb = lds_cb[j * 64 + lane];
            const double bx = (double)cb.x, by = (double)cb.y,
                         bz = (double)cb.z, bw = (double)cb.w;
            const int k = j * 64 + lane;
#pragma unroll
            for (int ii = 0; ii < 4; ++ii) {
                // d' = bsq - 2*dot  (x_sq constant over k: argmin-invariant)
                const double d = fma(bw, x2[ii][3],
                                 fma(bz, x2[ii][2],
                                 fma(by, x2[ii][1],
                                 fma(bx, x2[ii][0], bsq[j]))));
                if (d < bestd[ii]) { bestd[ii] = d; bestk[ii] = k; }
            }
        }

        // Wave argmin, lexicographic (d, k), 4 rows interleaved.
#pragma unroll
        for (int off = 32; off >= 1; off >>= 1) {
#pragma unroll
            for (int ii = 0; ii < 4; ++ii) {
                const double od = __shfl_xor(bestd[ii], off);
                const int    oi = __shfl_xor(bestk[ii], off);
                if (od < bestd[ii] || (od == bestd[ii] && oi < bestk[ii])) {
                    bestd[ii] = od; bestk[ii] = oi;
                }
            }
        }

#pragma unroll
        for (int ii = 0; ii < 4; ++ii) {
            const int b  = b_base + g * 4 + ii;
            const int bi = bestk[ii];
            if (lane == 0) {
                emb4[(size_t)b * C_DIM + c] = lds_cb[bi];
                idx_out[b * C_DIM + c]      = bi;   // K_ones reads it
            }
        }
    }
}

// ---------------------------------------------------------------------------
// K_ones: scatter the 131072 ones. One thread per (b*C+c) row.
// Runs after K_fused (kernel boundary orders the zero-fill and idx writes).
// ---------------------------------------------------------------------------
__global__ __launch_bounds__(256) void vq_scatter_ones(
    const int* __restrict__ idx_in,      // (B, C) flat
    float* __restrict__ out)             // one_hot at EMBED_ELEMS
{
    const int r = blockIdx.x * 256 + threadIdx.x;   // flat row, coalesced idx
    const int k = idx_in[r];
    out[EMBED_ELEMS + (size_t)r * K_DIM + k] = 1.0f;
}

extern "C" void kernel_launch(void* const* d_in, const int* in_sizes, int n_in,
                              void* d_out, int out_size, void* d_ws, size_t ws_size,
                              hipStream_t stream) {
    const float* cw_q     = (const float*)d_in[0];
    const float* codebook = (const float*)d_in[1];
    float* out = (float*)d_out;
    int*   idx = (int*)d_ws;   // 512 KB scratch

    vq_fused_kernel<<<C_DIM * (B_DIM / 32), 256, 0, stream>>>(cw_q, codebook, out, idx);
    vq_scatter_ones<<<(B_DIM * C_DIM) / 256, 256, 0, stream>>>(idx, out);
}